// Round 1
// 302.631 us; speedup vs baseline: 1.7637x; 1.7637x over previous
//
#include <hip/hip_runtime.h>

#define B_ 16
#define N_ 16384
#define K_ 16

// ---- workspace layout (float offsets) ----
enum : int {
  WS_LAT  = 0,      // 32 x 128 latent (f32, atomicMax-as-uint, relu>=0)
  WS_SEL  = 5632,   // 32 x 48 selected keypoints
  WS_PMIN = 7168,   // 16 x 3
  WS_PMAX = 7216,   // 16 x 3
  WS_CF   = 7264,   // 16 x 512 x 3 cage corners
  WS_W1F  = 31840,  // 64 x 3  bn-folded (fp32)
  WS_B1F  = 32032,  // 64
  // split-f16 B-fragment tables (MFMA layout), built by prep:
  WS_WB2H = 32096,  // 8192 f16 (4096 floats): layer2 B hi frags [nt*2+kt][lane][8]
  WS_WB2L = 36192,  // 8192 f16
  WS_B2F  = 40288,  // 128 fp32 folded bias
  WS_WB3H = 40416,  // 32768 f16 (16384 floats): layer3 B hi frags [nt*4+kt][lane][8]
  WS_B3F  = 56800,  // 128 fp32 folded bias
  WS_WB3L = 56928,  // 32768 f16 (16384 floats)
  WS_END  = 73312
};

enum : int { OUT_DEF=0, OUT_SRCKP=786432, OUT_TGTKP=787200 };

typedef _Float16 f16x8 __attribute__((ext_vector_type(8)));
typedef _Float16 f16x2 __attribute__((ext_vector_type(2)));
typedef float    f32x4 __attribute__((ext_vector_type(4)));

__device__ __forceinline__ float dist2rn(float px,float py,float pz,float sx,float sy,float sz){
  float dx=__fsub_rn(px,sx), dy=__fsub_rn(py,sy), dz=__fsub_rn(pz,sz);
  return __fadd_rn(__fadd_rn(__fmul_rn(dx,dx),__fmul_rn(dy,dy)),__fmul_rn(dz,dz));
}

// ---------------- prep: fold BN into encoder weights + split-f16 frags --------
struct EncW {
  const float *w1,*b1,*g1,*be1,*m1,*v1;
  const float *w2,*b2,*g2,*be2,*m2,*v2;
  const float *w3,*b3,*g3,*be3,*m3,*v3;
};

__device__ __forceinline__ float bn_scale(const float* g, const float* v, int ch){
  return g[ch] * (1.0f / sqrtf(v[ch] + 1e-5f));
}

__global__ void prep_kernel(EncW a, float* ws){
  const int stride = gridDim.x*blockDim.x;
  const int tid = blockIdx.x*blockDim.x + threadIdx.x;
  for (int i=tid;i<4096;i+=stride)            // zero latent (atomicMax target)
    ws[WS_LAT+i] = 0.0f;
  for (int i=tid;i<192;i+=stride){            // W1F (fp32: layer1 stays on VALU)
    int o=i/3;
    ws[WS_W1F+i] = a.w1[i] * bn_scale(a.g1,a.v1,o);
  }
  for (int i=tid;i<64;i+=stride){             // B1F
    float s = bn_scale(a.g1,a.v1,i);
    ws[WS_B1F+i] = (a.b1[i] - a.m1[i])*s + a.be1[i];
  }
  // layer2 B-frags, split f16 hi/lo. frag layout: lane l of MFMA B operand holds
  // B[k = kt*32 + (l>>4)*8 + j][col = nt*16 + (l&15)], j=0..7 contiguous.
  for (int i=tid;i<8192;i+=stride){
    int j = i & 7, frag = i >> 3;
    int l = frag & 63, nk = frag >> 6;        // nk = nt*2 + kt
    int kt = nk & 1, nt = nk >> 1;
    int c = kt*32 + ((l>>4)<<3) + j;          // 0..63 in-channel (K)
    int o = nt*16 + (l&15);                   // 0..127 out-channel (N)
    float v = a.w2[o*64+c] * bn_scale(a.g2,a.v2,o);
    _Float16 h = (_Float16)v;
    ((_Float16*)(ws+WS_WB2H))[i] = h;
    ((_Float16*)(ws+WS_WB2L))[i] = (_Float16)(v - (float)h);
  }
  for (int i=tid;i<128;i+=stride){
    float s = bn_scale(a.g2,a.v2,i);
    ws[WS_B2F+i] = (a.b2[i] - a.m2[i])*s + a.be2[i];
  }
  // layer3 B-frags, split f16 hi/lo
  for (int i=tid;i<32768;i+=stride){
    int j = i & 7, frag = i >> 3;
    int l = frag & 63, nk = frag >> 6;        // nk = nt*4 + kt
    int kt = nk & 3, nt = nk >> 2;
    int c = kt*32 + ((l>>4)<<3) + j;          // 0..127 in-channel (K)
    int o = nt*16 + (l&15);                   // 0..127 out-channel (N)
    float v = a.w3[o*128+c] * bn_scale(a.g3,a.v3,o);
    _Float16 h = (_Float16)v;
    ((_Float16*)(ws+WS_WB3H))[i] = h;
    ((_Float16*)(ws+WS_WB3L))[i] = (_Float16)(v - (float)h);
  }
  for (int i=tid;i<128;i+=stride){
    float s = bn_scale(a.g3,a.v3,i);
    ws[WS_B3F+i] = (a.b3[i] - a.m3[i])*s + a.be3[i];
  }
}

// ---------------- encoder v11: split-f16 MFMA for layers 2+3 ------------------
// R0 theory: v10 was VALU-FMA-issue-bound (VALUBusy 65%, MfmaUtil 0) within ~5%
// of the fp32 vector roofline. Move layers 2+3 (99% of MACs) to matrix cores
// with a 3-term split-f16 decomposition (AhBh + AhBl + AlBh): products exact in
// fp32 accum -> ~2^-21 relative error, below existing fp32-reorder noise, so
// FPS argmax selections are preserved.
// Structure: 128-pt tile/block, 512 thr = 8 waves in 2(M)x4(N) grid; wave owns
// 64 pts x 32 cols. Activations in LDS as hi/lo f16, rows XOR-swizzled
// (idx ^ ((row&7)<<3) in f16 units) so stride-128/256B ds_read_b128 A-frag
// reads are bank-conflict-free (T2/G4). Weights pre-split into B-frag order.
__global__ __launch_bounds__(512, 4) void encode_kernel(const float* __restrict__ src,
                                                        const float* __restrict__ tgt,
                                                        const float* __restrict__ ws,
                                                        float* __restrict__ lat){
  const int cloud = blockIdx.y;
  const int tile  = blockIdx.x;              // 128 tiles/cloud, 128 pts each
  const int t = threadIdx.x;
  const int lane = t & 63;
  const int wv = __builtin_amdgcn_readfirstlane(t >> 6);   // 0..7
  const int wm = wv >> 2;                    // 0..1 : rows 64*wm .. +63
  const int wn = wv & 3;                     // 0..3 : cols 32*wn .. +31
  const int lr = lane & 15;                  // row/col within 16x16 tile
  const int lg = lane >> 4;                  // k-group

  __shared__ alignas(16) _Float16 A[32768];  // 64KB
  _Float16* AH1 = A;                         // [128][64]  layer2 input hi
  _Float16* AL1 = A + 8192;                  //            layer2 input lo
  _Float16* AH2 = A;                         // [128][128] layer3 input hi (overlay)
  _Float16* AL2 = A + 16384;                 //            layer3 input lo

  const float* base = ((cloud < B_) ? (src + (size_t)cloud*N_*3)
                                    : (tgt + (size_t)(cloud-B_)*N_*3))
                      + (size_t)tile*128*3;

  // ---- layer 1 (3->64), fp32 VALU: thread t -> point t>>2, channels (t&3)*16..+15
  {
    const int pt = t >> 2, q = t & 3;
    const float x = base[pt*3+0], y = base[pt*3+1], z = base[pt*3+2];
    const float* w1 = ws + WS_W1F;
    const float* b1 = ws + WS_B1F;
    const int swz = (pt & 7) << 3;
    #pragma unroll
    for (int cc = 0; cc < 16; cc += 2){
      const int o = q*16 + cc;
      float v0 = fmaf(w1[o*3+2], z, fmaf(w1[o*3+1], y, w1[o*3+0]*x)) + b1[o];
      float v1 = fmaf(w1[o*3+5], z, fmaf(w1[o*3+4], y, w1[o*3+3]*x)) + b1[o+1];
      v0 = fmaxf(v0, 0.0f); v1 = fmaxf(v1, 0.0f);
      f16x2 h, l;
      h[0] = (_Float16)v0;              h[1] = (_Float16)v1;
      l[0] = (_Float16)(v0 - (float)h[0]); l[1] = (_Float16)(v1 - (float)h[1]);
      const int idx = (pt*64 + o) ^ swz;   // even, f16x2-aligned; XOR hits bits 3-5
      *(f16x2*)&AH1[idx] = h;
      *(f16x2*)&AL1[idx] = l;
    }
  }
  __syncthreads();

  // ---- layer 2 (64->128): M128 K64 N128, 3-term split MFMA
  f32x4 acc2[4][2];
  #pragma unroll
  for (int m=0;m<4;m++){
    #pragma unroll
    for (int n=0;n<2;n++) acc2[m][n] = (f32x4){0.f,0.f,0.f,0.f};
  }
  {
    const _Float16* wb2h = (const _Float16*)(ws + WS_WB2H);
    const _Float16* wb2l = (const _Float16*)(ws + WS_WB2L);
    const int swz = (lr & 7) << 3;
    #pragma unroll
    for (int kt=0; kt<2; kt++){
      f16x8 bh[2], bl[2];
      #pragma unroll
      for (int n=0;n<2;n++){
        const int fi = (((wn*2+n)*2 + kt)*64 + lane)*8;
        bh[n] = *(const f16x8*)(wb2h + fi);
        bl[n] = *(const f16x8*)(wb2l + fi);
      }
      #pragma unroll
      for (int m=0;m<4;m++){
        const int row = wm*64 + m*16 + lr;
        const int idx = (row*64 + kt*32 + lg*8) ^ swz;
        const f16x8 ah = *(const f16x8*)&AH1[idx];
        const f16x8 al = *(const f16x8*)&AL1[idx];
        #pragma unroll
        for (int n=0;n<2;n++){
          acc2[m][n] = __builtin_amdgcn_mfma_f32_16x16x32_f16(ah, bh[n], acc2[m][n], 0,0,0);
          acc2[m][n] = __builtin_amdgcn_mfma_f32_16x16x32_f16(ah, bl[n], acc2[m][n], 0,0,0);
          acc2[m][n] = __builtin_amdgcn_mfma_f32_16x16x32_f16(al, bh[n], acc2[m][n], 0,0,0);
        }
      }
    }
  }
  __syncthreads();   // all h1 reads complete before overlay write

  // h2 = relu(acc2 + b2): split hi/lo -> LDS (C layout: col=lr, rows lg*4+r)
  {
    const float* b2 = ws + WS_B2F;
    #pragma unroll
    for (int n=0;n<2;n++){
      const int ch = wn*32 + n*16 + lr;
      const float b = b2[ch];
      #pragma unroll
      for (int m=0;m<4;m++){
        #pragma unroll
        for (int r=0;r<4;r++){
          const int row = wm*64 + m*16 + lg*4 + r;
          const float v = fmaxf(acc2[m][n][r] + b, 0.0f);
          const _Float16 hi = (_Float16)v;
          const _Float16 lo = (_Float16)(v - (float)hi);
          const int idx = (row*128 + ch) ^ ((row & 7) << 3);
          AH2[idx] = hi;
          AL2[idx] = lo;
        }
      }
    }
  }
  __syncthreads();

  // ---- layer 3 (128->128): M128 K128 N128, 3-term split MFMA
  f32x4 acc3[4][2];
  #pragma unroll
  for (int m=0;m<4;m++){
    #pragma unroll
    for (int n=0;n<2;n++) acc3[m][n] = (f32x4){0.f,0.f,0.f,0.f};
  }
  {
    const _Float16* wb3h = (const _Float16*)(ws + WS_WB3H);
    const _Float16* wb3l = (const _Float16*)(ws + WS_WB3L);
    const int swz = (lr & 7) << 3;
    #pragma unroll
    for (int kt=0; kt<4; kt++){
      f16x8 bh[2], bl[2];
      #pragma unroll
      for (int n=0;n<2;n++){
        const int fi = (((wn*2+n)*4 + kt)*64 + lane)*8;
        bh[n] = *(const f16x8*)(wb3h + fi);
        bl[n] = *(const f16x8*)(wb3l + fi);
      }
      #pragma unroll
      for (int m=0;m<4;m++){
        const int row = wm*64 + m*16 + lr;
        const int idx = (row*128 + kt*32 + lg*8) ^ swz;
        const f16x8 ah = *(const f16x8*)&AH2[idx];
        const f16x8 al = *(const f16x8*)&AL2[idx];
        #pragma unroll
        for (int n=0;n<2;n++){
          acc3[m][n] = __builtin_amdgcn_mfma_f32_16x16x32_f16(ah, bh[n], acc3[m][n], 0,0,0);
          acc3[m][n] = __builtin_amdgcn_mfma_f32_16x16x32_f16(ah, bl[n], acc3[m][n], 0,0,0);
          acc3[m][n] = __builtin_amdgcn_mfma_f32_16x16x32_f16(al, bh[n], acc3[m][n], 0,0,0);
        }
      }
    }
  }

  // epilogue: bias+relu, max over this wave's 64 rows, cross-group shfl, atomic
  {
    const float* b3 = ws + WS_B3F;
    #pragma unroll
    for (int n=0;n<2;n++){
      const int ch = wn*32 + n*16 + lr;
      const float b = b3[ch];
      float x = 0.0f;                        // relu floor
      #pragma unroll
      for (int m=0;m<4;m++){
        #pragma unroll
        for (int r=0;r<4;r++)
          x = fmaxf(x, acc3[m][n][r] + b);
      }
      x = fmaxf(x, __shfl_xor(x, 16, 64));
      x = fmaxf(x, __shfl_xor(x, 32, 64));
      if (lane < 16)
        atomicMax((unsigned*)(lat + cloud*128 + ch), __float_as_uint(x));
    }
  }
}

// ---------------- FPS + fused kp-MLP + fused src min/max ----------------------
__global__ __launch_bounds__(512) void fps_kernel(const float* __restrict__ src,
                                                  const float* __restrict__ tgt,
                                                  const float* __restrict__ kw1,
                                                  const float* __restrict__ kb1,
                                                  const float* __restrict__ kw2,
                                                  const float* __restrict__ kb2,
                                                  float* ws, float* out){
  const int cloud = blockIdx.x; const int t = threadIdx.x;
  const float* base = (cloud < B_) ? (src + (size_t)cloud*N_*3)
                                   : (tgt + (size_t)(cloud-B_)*N_*3);
  __shared__ float kpl[48];
  __shared__ float h[128];
  __shared__ float rv[512]; __shared__ int ri[512];
  __shared__ float sel[3];

  float px[32], py[32], pz[32];
  #pragma unroll
  for (int k=0;k<32;k++){
    int n = t + k*512;
    px[k]=base[n*3]; py[k]=base[n*3+1]; pz[k]=base[n*3+2];
  }

  const float* lat = ws + WS_LAT + cloud*128;
  if (t < 128){
    float acc = kb1[t];
    const float* w = kw1 + t*128;
    for (int c=0;c<128;c++) acc = fmaf(lat[c], w[c], acc);
    h[t] = fmaxf(acc, 0.0f);
  }
  __syncthreads();
  if (t < 48){
    float acc = kb2[t];
    const float* w = kw2 + t*128;
    for (int c=0;c<128;c++) acc = fmaf(h[c], w[c], acc);
    kpl[t] = acc;
  }
  __syncthreads();

  float mnx=3.4e38f,mny=3.4e38f,mnz=3.4e38f, mxx=-3.4e38f,mxy=-3.4e38f,mxz=-3.4e38f;
  float bv = -1.0f; int bi = 0;
  #pragma unroll 2
  for (int k=0;k<32;k++){
    int n = t + k*512;
    if (cloud < B_){
      mnx=fminf(mnx,px[k]); mny=fminf(mny,py[k]); mnz=fminf(mnz,pz[k]);
      mxx=fmaxf(mxx,px[k]); mxy=fmaxf(mxy,py[k]); mxz=fmaxf(mxz,pz[k]);
    }
    float dmin = 3.4028235e38f;
    #pragma unroll
    for (int j=0;j<K_;j++)
      dmin = fminf(dmin, dist2rn(px[k],py[k],pz[k], kpl[j*3],kpl[j*3+1],kpl[j*3+2]));
    if (dmin > bv){ bv = dmin; bi = n; }
  }

  rv[t]=bv; ri[t]=bi;
  __syncthreads();
  if (t < 64){
    float v = rv[t]; int i = ri[t];
    #pragma unroll
    for (int e=1;e<8;e++){
      float v2=rv[t+64*e]; int i2=ri[t+64*e];
      if (v2 > v || (v2 == v && i2 < i)){ v=v2; i=i2; }
    }
    #pragma unroll
    for (int m=1;m<64;m<<=1){
      float v2=__shfl_xor(v,m,64); int i2=__shfl_xor(i,m,64);
      if (v2 > v || (v2 == v && i2 < i)){ v=v2; i=i2; }
    }
    if (t==0){
      sel[0]=base[i*3]; sel[1]=base[i*3+1]; sel[2]=base[i*3+2];
      float* sw = ws + WS_SEL + cloud*48;
      sw[0]=sel[0]; sw[1]=sel[1]; sw[2]=sel[2];
      size_t o = (cloud<B_) ? (size_t)(OUT_SRCKP + cloud*48) : (size_t)(OUT_TGTKP + (cloud-B_)*48);
      out[o]=sel[0]; out[o+1]=sel[1]; out[o+2]=sel[2];
    }
  }
  __syncthreads();

  if (cloud < B_){
    float vals[6] = {mnx,mny,mnz,mxx,mxy,mxz};
    for (int c=0;c<6;c++){
      rv[t]=vals[c];
      __syncthreads();
      if (t < 64){
        float v = rv[t];
        #pragma unroll
        for (int e=1;e<8;e++){
          float v2 = rv[t+64*e];
          v = (c<3) ? fminf(v,v2) : fmaxf(v,v2);
        }
        #pragma unroll
        for (int m=1;m<64;m<<=1){
          float v2=__shfl_xor(v,m,64);
          v = (c<3) ? fminf(v,v2) : fmaxf(v,v2);
        }
        if (t==0){
          if (c<3) ws[WS_PMIN + cloud*3 + c] = v;
          else     ws[WS_PMAX + cloud*3 + (c-3)] = v;
        }
      }
      __syncthreads();
    }
  }

  float s0=sel[0], s1=sel[1], s2=sel[2];

  float mind[32];
  bv = -1.0f; bi = 0;
  #pragma unroll
  for (int k=0;k<32;k++){
    int n = t + k*512;
    float d = dist2rn(px[k],py[k],pz[k], s0,s1,s2);
    mind[k]=d;
    if (d > bv){ bv=d; bi=n; }
  }

  for (int it=1; it<K_; it++){
    rv[t]=bv; ri[t]=bi;
    __syncthreads();
    if (t < 64){
      float v = rv[t]; int i = ri[t];
      #pragma unroll
      for (int e=1;e<8;e++){
        float v2=rv[t+64*e]; int i2=ri[t+64*e];
        if (v2 > v || (v2 == v && i2 < i)){ v=v2; i=i2; }
      }
      #pragma unroll
      for (int m=1;m<64;m<<=1){
        float v2=__shfl_xor(v,m,64); int i2=__shfl_xor(i,m,64);
        if (v2 > v || (v2 == v && i2 < i)){ v=v2; i=i2; }
      }
      if (t==0){
        sel[0]=base[i*3]; sel[1]=base[i*3+1]; sel[2]=base[i*3+2];
        float* sw = ws + WS_SEL + cloud*48 + it*3;
        sw[0]=sel[0]; sw[1]=sel[1]; sw[2]=sel[2];
        size_t o = (cloud<B_) ? (size_t)(OUT_SRCKP + cloud*48 + it*3)
                              : (size_t)(OUT_TGTKP + (cloud-B_)*48 + it*3);
        out[o]=sel[0]; out[o+1]=sel[1]; out[o+2]=sel[2];
      }
    }
    __syncthreads();
    s0=sel[0]; s1=sel[1]; s2=sel[2];
    if (it < K_-1){
      bv=-1.0f; bi=0;
      #pragma unroll
      for (int k=0;k<32;k++){
        int n = t + k*512;
        float d = dist2rn(px[k],py[k],pz[k], s0,s1,s2);
        float m = fminf(mind[k], d);
        mind[k]=m;
        if (m > bv){ bv=m; bi=n; }
      }
    }
  }
}

// ---------------- cage MLP + corner grid (64 blocks) --------------------------
__global__ void cage_mlp_kernel(const float* __restrict__ ws,
                                const float* __restrict__ cw1, const float* __restrict__ cb1,
                                const float* __restrict__ cw2, const float* __restrict__ cb2,
                                float* __restrict__ wsm){
  const int b = blockIdx.x >> 2, part = blockIdx.x & 3;
  const int t = threadIdx.x;
  __shared__ float diff[48]; __shared__ float h[128];
  if (t<48) diff[t] = __fsub_rn(ws[WS_SEL + (B_+b)*48 + t], ws[WS_SEL + b*48 + t]);
  __syncthreads();
  if (t<128){
    const float* w = cw1 + t*48;
    float acc = cb1[t];
    for (int j=0;j<48;j++) acc = fmaf(diff[j], w[j], acc);
    h[t] = fmaxf(acc, 0.0f);
  }
  __syncthreads();
  for (int o = part*384 + t; o < part*384 + 384; o += 256){
    const float* w = cw2 + o*128;
    float acc = cb2[o];
    for (int c=0;c<128;c++) acc = fmaf(h[c], w[c], acc);
    int flat = o/3, coord = o - flat*3;
    int u = flat>>6, v=(flat>>3)&7, z=flat&7;
    int g = (coord==0)?u:((coord==1)?v:z);
    float gv = (g==7)?1.0f:(float)g*(1.0f/7.0f);
    wsm[WS_CF + b*1536 + o] = gv + acc;
  }
}

// ---------------- trilinear cage deform ---------------------------------------
__global__ __launch_bounds__(256) void deform_kernel(const float* __restrict__ src,
                                                     const float* __restrict__ ws,
                                                     float* __restrict__ out){
  const int b = blockIdx.y;
  const int n = blockIdx.x*256 + threadIdx.x;
  __shared__ float cf[1536];
  for (int i=threadIdx.x;i<1536;i+=256) cf[i] = ws[WS_CF + b*1536 + i];
  __syncthreads();

  const float* p = src + ((size_t)b*N_ + n)*3;
  float pt[3]; int id[3]; float w[3];
  #pragma unroll
  for (int c=0;c<3;c++){
    float pv = p[c];
    float mn = ws[WS_PMIN+b*3+c], mxv = ws[WS_PMAX+b*3+c];
    float denom = __fadd_rn(__fsub_rn(mxv, mn), 1e-6f);
    float tc = __fmul_rn(__fdiv_rn(__fsub_rn(pv, mn), denom), 7.0f);
    int ic = (int)tc; ic = min(max(ic,0),6);
    pt[c]=pv; id[c]=ic; w[c]=__fsub_rn(tc, (float)ic);
  }
  const int flat = (id[0]<<6) + (id[1]<<3) + id[2];
  const float* c000 = cf + flat*3;
  const float wx=w[0], wy=w[1], wz=w[2];
  const float ux=__fsub_rn(1.0f,wx), uy=__fsub_rn(1.0f,wy), uz=__fsub_rn(1.0f,wz);
  const float w000=__fmul_rn(__fmul_rn(ux,uy),uz);
  const float w100=__fmul_rn(__fmul_rn(wx,uy),uz);
  const float w010=__fmul_rn(__fmul_rn(ux,wy),uz);
  const float w110=__fmul_rn(__fmul_rn(wx,wy),uz);
  const float w001=__fmul_rn(__fmul_rn(ux,uy),wz);
  const float w101=__fmul_rn(__fmul_rn(wx,uy),wz);
  const float w011=__fmul_rn(__fmul_rn(ux,wy),wz);
  const float w111=__fmul_rn(__fmul_rn(wx,wy),wz);
  #pragma unroll
  for (int c=0;c<3;c++){
    float d = __fmul_rn(w000, c000[c]);
    d = __fadd_rn(d, __fmul_rn(w100, c000[192+c]));
    d = __fadd_rn(d, __fmul_rn(w010, c000[24+c]));
    d = __fadd_rn(d, __fmul_rn(w110, c000[216+c]));
    d = __fadd_rn(d, __fmul_rn(w001, c000[3+c]));
    d = __fadd_rn(d, __fmul_rn(w101, c000[195+c]));
    d = __fadd_rn(d, __fmul_rn(w011, c000[27+c]));
    d = __fadd_rn(d, __fmul_rn(w111, c000[219+c]));
    out[((size_t)b*N_+n)*3 + c] = __fadd_rn(pt[c], d);
  }
}

// ---------------- launch ------------------------------------------------------
extern "C" void kernel_launch(void* const* d_in, const int* in_sizes, int n_in,
                              void* d_out, int out_size, void* d_ws, size_t ws_size,
                              hipStream_t stream){
  const float* src = (const float*)d_in[0];
  const float* tgt = (const float*)d_in[1];
  float* ws = (float*)d_ws;
  float* out = (float*)d_out;

  EncW ew;
  ew.w1 =(const float*)d_in[2];  ew.b1 =(const float*)d_in[3];
  ew.g1 =(const float*)d_in[4];  ew.be1=(const float*)d_in[5];
  ew.m1 =(const float*)d_in[6];  ew.v1 =(const float*)d_in[7];
  ew.w2 =(const float*)d_in[8];  ew.b2 =(const float*)d_in[9];
  ew.g2 =(const float*)d_in[10]; ew.be2=(const float*)d_in[11];
  ew.m2 =(const float*)d_in[12]; ew.v2 =(const float*)d_in[13];
  ew.w3 =(const float*)d_in[14]; ew.b3 =(const float*)d_in[15];
  ew.g3 =(const float*)d_in[16]; ew.be3=(const float*)d_in[17];
  ew.m3 =(const float*)d_in[18]; ew.v3 =(const float*)d_in[19];

  prep_kernel<<<128, 256, 0, stream>>>(ew, ws);
  encode_kernel<<<dim3(128,32), 512, 0, stream>>>(src, tgt, ws, ws + WS_LAT);
  fps_kernel<<<32, 512, 0, stream>>>(src, tgt,
      (const float*)d_in[20], (const float*)d_in[21],
      (const float*)d_in[22], (const float*)d_in[23], ws, out);
  cage_mlp_kernel<<<64, 256, 0, stream>>>(ws,
      (const float*)d_in[24], (const float*)d_in[25],
      (const float*)d_in[26], (const float*)d_in[27], ws);
  deform_kernel<<<dim3(64,16), 256, 0, stream>>>(src, ws, out);
}